// Round 7
// baseline (299.859 us; speedup 1.0000x reference)
//
#include <hip/hip_runtime.h>
#include <math.h>

// Problem constants (fixed by setup_inputs)
constexpr int K_ = 4, B_ = 8, T_ = 800, C_ = 80, S_ = 128, Z_ = 32;
constexpr int KB_ = K_ * B_;        // 32
constexpr int TC_ = T_ * C_;        // 64000

#define BIGV   1e8f
#define WARP_V 256.0f

// Block-anti-diagonal banded D layout:
//   cell (i, c) 0-based -> row-block t = i>>2, d2 = t + c, slot = t - tmin(d2),
//   stored as float4 (4 rows) at D2[d2*W2*4 + slot*4].
// Band: c - 4t in [-124, 127] (== the DP's active window) -> slot width <= 51.
constexpr int W2_   = 52;
constexpr int PD2_  = 1000;               // d2 in [0, 998]
constexpr int SLAB2_ = PD2_ * W2_ * 4;    // 208,000 floats per problem

__device__ __forceinline__ int tmin_of(int d2) {
    int t = (d2 - 123) / 5;               // == max(0, ceil((d2-127)/5)) for d2>=0
    return t > 0 ? t : 0;
}

__device__ __forceinline__ float sigmoidf_(float v) {
    return 1.f / (1.f + __expf(-v));
}

// ---------------------------------------------------------------- banded GEMM -> D2 (norms fused)
// grid (5, 13, 32): tiles with |ti-tj| <= 2 (covers the |i-j| <= 127 DP band: 64*3-63=129 > 127).
__global__ __launch_bounds__(256) void gemm_band(const float* __restrict__ mel_iters,
                                                 const float* __restrict__ mel_targets,
                                                 float* __restrict__ Dm) {
    const int kb = blockIdx.z;
    const int b  = kb & 7;
    const int ti = blockIdx.y;
    const int tj = ti + (int)blockIdx.x - 2;
    if ((unsigned)tj > 12u) return;

    const float* __restrict__ Xb = mel_iters + (size_t)kb * TC_;
    const float* __restrict__ Yb = mel_targets + (size_t)b * TC_;

    __shared__ float xa[16][68];   // [k][i] (sigmoid applied)
    __shared__ float ya[16][68];   // [k][j]
    __shared__ float x2s[64], y2s[64];

    const int tid = threadIdx.x;
    const int tx = tid & 15, ty = tid >> 4;
    const int i0 = ti * 64, j0 = tj * 64;
    const int lr = tid >> 4;   // 0..15
    const int lc = tid & 15;   // 0..15  (k within chunk)

    float acc[4][4] = {};
    float nsum = 0.f;          // row-norm partial (tid<64: x2 row tid; tid in [64,128): y2)

    for (int kk = 0; kk < C_; kk += 16) {
        __syncthreads();
        #pragma unroll
        for (int q = 0; q < 4; ++q) {
            int row = lr + q * 16;       // 0..63
            int gi = i0 + row;
            xa[lc][row] = (gi < T_) ? sigmoidf_(Xb[(size_t)gi * C_ + kk + lc]) : 0.f;
            int gj = j0 + row;
            ya[lc][row] = (gj < T_) ? sigmoidf_(Yb[(size_t)gj * C_ + kk + lc]) : 0.f;
        }
        __syncthreads();
        if (tid < 64) {
            #pragma unroll
            for (int k = 0; k < 16; ++k) { float v = xa[k][tid]; nsum += v * v; }
        } else if (tid < 128) {
            #pragma unroll
            for (int k = 0; k < 16; ++k) { float v = ya[k][tid - 64]; nsum += v * v; }
        }
        #pragma unroll
        for (int k = 0; k < 16; ++k) {
            float4 av = *(const float4*)&xa[k][ty * 4];
            float4 bv = *(const float4*)&ya[k][tx * 4];
            acc[0][0] += av.x * bv.x; acc[0][1] += av.x * bv.y; acc[0][2] += av.x * bv.z; acc[0][3] += av.x * bv.w;
            acc[1][0] += av.y * bv.x; acc[1][1] += av.y * bv.y; acc[1][2] += av.y * bv.z; acc[1][3] += av.y * bv.w;
            acc[2][0] += av.z * bv.x; acc[2][1] += av.z * bv.y; acc[2][2] += av.z * bv.z; acc[2][3] += av.z * bv.w;
            acc[3][0] += av.w * bv.x; acc[3][1] += av.w * bv.y; acc[3][2] += av.w * bv.z; acc[3][3] += av.w * bv.w;
        }
    }
    if (tid < 64) x2s[tid] = nsum;
    else if (tid < 128) y2s[tid - 64] = nsum;
    __syncthreads();

    // epilogue: D[i][j] = x2[i] + y2[j] - 2*dot into block-anti-diagonal layout
    const int ib = i0 + ty * 4, jb = j0 + tx * 4;
    if (ib >= T_) return;   // ib 4-aligned, T_=800 -> all-or-nothing
    float xs2[4], ys2[4];
    #pragma unroll
    for (int r = 0; r < 4; ++r) xs2[r] = x2s[ty * 4 + r];
    #pragma unroll
    for (int c = 0; c < 4; ++c) ys2[c] = y2s[tx * 4 + c];

    const int tblk = ib >> 2;
    float* __restrict__ D2b = Dm + (size_t)kb * SLAB2_;
    #pragma unroll
    for (int c = 0; c < 4; ++c) {
        int j = jb + c;
        if (j >= T_) continue;
        int d2 = tblk + j;
        int sl = tblk - tmin_of(d2);
        if ((unsigned)sl > (unsigned)(W2_ - 1)) continue;   // out of DP band: never read
        float4 o;
        o.x = xs2[0] + ys2[c] - 2.f * acc[0][c];
        o.y = xs2[1] + ys2[c] - 2.f * acc[1][c];
        o.z = xs2[2] + ys2[c] - 2.f * acc[2][c];
        o.w = xs2[3] + ys2[c] - 2.f * acc[3][c];
        *(float4*)(D2b + (size_t)d2 * (W2_ * 4) + sl * 4) = o;
    }
}

// ---------------------------------------------------------------- banded hard-min DTW, r=4 systolic
// One block (256 thr = 4 waves) per problem; 1 wave per SIMD. Thread t owns DP
// rows 4t+1..4t+4 (1-based), sweeps columns [i0-124, i0+127], lane skew 1,
// wave skew G=80, barrier every 8 steps. D2 loads are COALESCED (d2 lane-
// invariant, slot = 64w+l-tmin -> consecutive float4 per lane), unconditional
// clamped, 3-phase (24-step, ~1050 cyc) register lookahead.
constexpr int G3_   = 80;
constexpr int NPH3_ = 132;   // 132*8 = 1056 > last active step 1046; 132 = 3*44

__device__ __forceinline__ void lds_barrier_keep_vmcnt() {
    asm volatile("" ::: "memory");
    // simm16: vmcnt=63 (keep global loads in flight), expcnt=7, lgkmcnt=0
    __builtin_amdgcn_s_waitcnt(0xC07F);
    __builtin_amdgcn_s_barrier();
    asm volatile("" ::: "memory");
}

__device__ __forceinline__ float wave_shr1(float x) {
    // DPP wave_shr1 (0x138): lane l gets lane l-1's value; lane 0 -> 0 (overridden)
    int v = __builtin_amdgcn_update_dpp(0, __float_as_int(x), 0x138, 0xf, 0xf, true);
    return __int_as_float(v);
}

__global__ __launch_bounds__(256) void dtw_hard_kernel(const float* __restrict__ Dm,
                                                       float* __restrict__ dtwv) {
    __shared__ float ring[3 * 64];
    const int kb  = blockIdx.x;
    const int tid = threadIdx.x;
    const int w = tid >> 6, l = tid & 63;
    const int wu = __builtin_amdgcn_readfirstlane(w);
    const bool owner  = tid < 200;                 // 200 lanes x 4 rows = 800
    const bool is_l0  = (l == 0);
    const bool is_l63w = (l == 63) && (wu < 3);    // ring writers
    const int  i0 = 4 * tid + 1;                   // top DP row (1-based)
    const float* __restrict__ Dd = Dm + (size_t)kb * SLAB2_;

    // per-lane active column window [jlo, jhi]
    const int jlo = owner ? max(1, i0 - 124) : (1 << 29);
    const int jhi_ = min(T_, i0 + 127);
    const unsigned spanu = owner ? (unsigned)(jhi_ - jlo) : 0u;
    const float dg1 = (tid == 0) ? 0.f : BIGV;     // R[i-1][0] override at jj==1

    const int goff = G3_ * wu;
    const int wm1 = (wu > 0 ? wu - 1 : 0) * 64;
    const int low_w  = max(1, 256 * wu - 127);
    const int high_w = min(800, 256 * wu + 124);
    const int rslot = wu * 64;

    if (tid < 192) ring[tid] = BIGV;
    __syncthreads();

    // DP state: R[4t+1..4t+4][jj-1] in registers; tprev = R[4t][jj-1]
    float r0s = BIGV, r1s = BIGV, r2s = BIGV, r3s = BIGV;
    float tprev = BIGV;
    int jj = 1 - goff - l;                         // this lane's column at step 0

    // Coalesced clamped D2 load for global step s (d2 wave-uniform)
    auto load_d2 = [&](int s) -> float4 {
        int d2 = s - 16 * wu;                      // t + c = (64w+l) + (s-80w-l)
        d2 = d2 < 0 ? 0 : (d2 > PD2_ - 1 ? PD2_ - 1 : d2);
        int sl = 64 * wu + l - tmin_of(d2);
        sl = sl < 0 ? 0 : (sl > W2_ - 1 ? W2_ - 1 : sl);
        return *(const float4*)(Dd + (size_t)d2 * (W2_ * 4) + sl * 4);
    };

    // D lookahead buffers: phases p, p+1, p+2; refill for p+3 during p
    float4 bufA[8], bufB[8], bufC[8];
    #pragma unroll
    for (int k = 0; k < 8; ++k) {
        bufA[k] = load_d2(k);
        bufB[k] = load_d2(k + 8);
        bufC[k] = load_d2(k + 16);
    }

    float rvA[8], rvB[8], rvC[8];
    auto prefetch_ring = [&](float (&rv)[8], int pp) {   // values consumed during phase pp
        #pragma unroll
        for (int k = 0; k < 8; ++k) {
            int j0 = 8 * pp + k + 1 - goff;              // lane-0 column at step 8*pp+k
            float rr = ring[wm1 + (j0 & 63)];
            rv[k] = (wu > 0 && j0 >= low_w && j0 <= high_w) ? rr : BIGV;
        }
    };

    auto run8 = [&](float4 (&buf)[8], const float (&rv)[8], int sp) {
        #pragma unroll
        for (int k = 0; k < 8; ++k) {
            float4 d = buf[k];
            buf[k] = load_d2(sp + k + 24);               // refill phase p+3, stays in flight
            float tin  = wave_shr1(r3s);                 // lane l-1's bottom value (prev step)
            float tcur = is_l0 ? rv[k] : tin;            // R[i0-1][jj]
            float dg   = (jj == 1) ? dg1 : tprev;        // R[i0-1][jj-1]
            float dxW = d.x + WARP_V;
            float n0 = fminf(fminf(dg + d.x, tcur + dxW), r0s + dxW);
            float dyW = d.y + WARP_V;
            float n1 = fminf(fminf(r0s + d.y, n0 + dyW), r1s + dyW);
            float dzW = d.z + WARP_V;
            float n2 = fminf(fminf(r1s + d.z, n1 + dzW), r2s + dzW);
            float dwW = d.w + WARP_V;
            float n3 = fminf(fminf(r2s + d.w, n2 + dwW), r3s + dwW);
            bool act = (unsigned)(jj - jlo) <= spanu;
            if (act && is_l63w) ring[rslot + (jj & 63)] = n3;
            r0s = act ? n0 : r0s;
            r1s = act ? n1 : r1s;
            r2s = act ? n2 : r2s;
            r3s = act ? n3 : r3s;
            tprev = tcur;
            ++jj;
        }
    };

    prefetch_ring(rvA, 0);    // phase 0: all masked (no writes possible yet)

    for (int p = 0; p < NPH3_; p += 3) {
        prefetch_ring(rvB, p + 1);     // ring writes needed: steps <= 8p-2, visible
        run8(bufA, rvA, 8 * p);
        lds_barrier_keep_vmcnt();
        prefetch_ring(rvC, p + 2);     // needed <= 8p+7, visible after barrier p
        run8(bufB, rvB, 8 * (p + 1));
        lds_barrier_keep_vmcnt();
        prefetch_ring(rvA, p + 3);     // needed <= 8p+15, visible after barrier p+1
        run8(bufC, rvC, 8 * (p + 2));
        lds_barrier_keep_vmcnt();
    }

    // tid 199 (rows 797..800) ends its window at jj=800 -> r3s = R[800][800]
    if (tid == 199) dtwv[kb] = r3s;
}

// ---------------------------------------------------------------- finalize (scalars)
__global__ void finalize_kernel(const float* __restrict__ dtwv, const int* __restrict__ mel_lens,
                                const int* __restrict__ src_lens, const float* __restrict__ durations,
                                const float* __restrict__ mus, const float* __restrict__ log_vars,
                                const int* __restrict__ step, float* __restrict__ out) {
    const int lane = threadIdx.x;  // 64 threads, one wave

    float v = (lane < KB_) ? dtwv[lane] : 0.f;
    for (int o = 32; o; o >>= 1) v += __shfl_down(v, o);

    float w = (lane < B_) ? 1.f / (K_ * (float)mel_lens[lane]) : 0.f;
    for (int o = 32; o; o >>= 1) w += __shfl_down(w, o);

    float du = 0.f;
    if (lane < B_) {
        float s = 0.f;
        for (int j = 0; j < S_; ++j) s += durations[lane * S_ + j];
        du = fabsf(s - (float)mel_lens[lane]) / (float)src_lens[lane];
    }
    for (int o = 32; o; o >>= 1) du += __shfl_down(du, o);

    float kl = 0.f;
    for (int j = lane; j < B_ * Z_; j += 64) {
        float muv = mus[j], lv = log_vars[j];
        kl += 1.f + lv - muv * muv - expf(lv);
    }
    for (int o = 32; o; o >>= 1) kl += __shfl_down(kl, o);

    if (lane == 0) {
        float mel_iter_loss = v / (float)B_;
        float mel_loss = mel_iter_loss * (w / (float)B_);
        float dur_loss = 2.0f * du / (float)B_;
        float kl_loss = -0.5f * kl;
        int st = step[0];
        float beta = (st < 2000) ? 0.f : ((st >= 8000) ? 1.f : (float)(st - 2000) / 6000.f);
        out[0] = mel_loss + dur_loss + beta * kl_loss;
        out[1] = mel_loss;
        out[2] = dur_loss;
        out[3] = kl_loss;
        out[4] = beta;
    }
}

// ---------------------------------------------------------------- launch
extern "C" void kernel_launch(void* const* d_in, const int* in_sizes, int n_in,
                              void* d_out, int out_size, void* d_ws, size_t ws_size,
                              hipStream_t stream) {
    const float* mel_iters   = (const float*)d_in[0];
    const float* mel_targets = (const float*)d_in[1];
    const int*   mel_lens    = (const int*)d_in[2];
    const int*   src_lens    = (const int*)d_in[3];
    const float* durations   = (const float*)d_in[4];
    const float* mus         = (const float*)d_in[5];
    const float* log_vars    = (const float*)d_in[6];
    const int*   step        = (const int*)d_in[7];
    float* out = (float*)d_out;

    float* ws   = (float*)d_ws;
    float* Dm   = ws;                              // 32 * 208,000 = 6,656,000 floats (26.6 MB)
    float* dtwv = Dm + (size_t)KB_ * SLAB2_;       //        32

    gemm_band<<<dim3(5, 13, KB_), 256, 0, stream>>>(mel_iters, mel_targets, Dm);

    dtw_hard_kernel<<<KB_, 256, 0, stream>>>(Dm, dtwv);

    finalize_kernel<<<1, 64, 0, stream>>>(dtwv, mel_lens, src_lens, durations, mus, log_vars, step, out);
}

// Round 8
// 278.396 us; speedup vs baseline: 1.0771x; 1.0771x over previous
//
#include <hip/hip_runtime.h>
#include <math.h>

// Problem constants (fixed by setup_inputs)
constexpr int K_ = 4, B_ = 8, T_ = 800, C_ = 80, S_ = 128, Z_ = 32;
constexpr int KB_ = K_ * B_;        // 32
constexpr int TC_ = T_ * C_;        // 64000

#define BIGV   1e8f
#define WARP_V 256.0f

// Block-anti-diagonal banded D layout:
//   cell (i, c) 0-based -> row-block t = i>>2, d2 = t + c, slot = t - tmin(d2),
//   stored as float4 (4 rows) at D2[d2*W2*4 + slot*4].
// Band: c - 4t in [-124, 127] (== the DP's active window) -> slot width <= 51.
constexpr int W2_   = 52;
constexpr int PD2_  = 1000;               // d2 in [0, 998]
constexpr int SLAB2_ = PD2_ * W2_ * 4;    // 208,000 floats per problem

__device__ __forceinline__ int tmin_of(int d2) {
    int t = (d2 - 123) / 5;               // == max(0, ceil((d2-127)/5)) for d2>=0
    return t > 0 ? t : 0;
}

__device__ __forceinline__ float sigmoidf_(float v) {
    return 1.f / (1.f + __expf(-v));
}

// ---------------------------------------------------------------- banded GEMM -> D2 (norms fused)
// grid (5, 13, 32): tiles with |ti-tj| <= 2 (covers the |i-j| <= 127 DP band).
__global__ __launch_bounds__(256) void gemm_band(const float* __restrict__ mel_iters,
                                                 const float* __restrict__ mel_targets,
                                                 float* __restrict__ Dm) {
    const int kb = blockIdx.z;
    const int b  = kb & 7;
    const int ti = blockIdx.y;
    const int tj = ti + (int)blockIdx.x - 2;
    if ((unsigned)tj > 12u) return;

    const float* __restrict__ Xb = mel_iters + (size_t)kb * TC_;
    const float* __restrict__ Yb = mel_targets + (size_t)b * TC_;

    __shared__ float xa[16][68];   // [k][i] (sigmoid applied)
    __shared__ float ya[16][68];   // [k][j]
    __shared__ float x2s[64], y2s[64];

    const int tid = threadIdx.x;
    const int tx = tid & 15, ty = tid >> 4;
    const int i0 = ti * 64, j0 = tj * 64;
    const int lr = tid >> 4;   // 0..15
    const int lc = tid & 15;   // 0..15  (k within chunk)

    float acc[4][4] = {};
    float nsum = 0.f;          // row-norm partial (tid<64: x2 row tid; tid in [64,128): y2)

    for (int kk = 0; kk < C_; kk += 16) {
        __syncthreads();
        #pragma unroll
        for (int q = 0; q < 4; ++q) {
            int row = lr + q * 16;       // 0..63
            int gi = i0 + row;
            xa[lc][row] = (gi < T_) ? sigmoidf_(Xb[(size_t)gi * C_ + kk + lc]) : 0.f;
            int gj = j0 + row;
            ya[lc][row] = (gj < T_) ? sigmoidf_(Yb[(size_t)gj * C_ + kk + lc]) : 0.f;
        }
        __syncthreads();
        if (tid < 64) {
            #pragma unroll
            for (int k = 0; k < 16; ++k) { float v = xa[k][tid]; nsum += v * v; }
        } else if (tid < 128) {
            #pragma unroll
            for (int k = 0; k < 16; ++k) { float v = ya[k][tid - 64]; nsum += v * v; }
        }
        #pragma unroll
        for (int k = 0; k < 16; ++k) {
            float4 av = *(const float4*)&xa[k][ty * 4];
            float4 bv = *(const float4*)&ya[k][tx * 4];
            acc[0][0] += av.x * bv.x; acc[0][1] += av.x * bv.y; acc[0][2] += av.x * bv.z; acc[0][3] += av.x * bv.w;
            acc[1][0] += av.y * bv.x; acc[1][1] += av.y * bv.y; acc[1][2] += av.y * bv.z; acc[1][3] += av.y * bv.w;
            acc[2][0] += av.z * bv.x; acc[2][1] += av.z * bv.y; acc[2][2] += av.z * bv.z; acc[2][3] += av.z * bv.w;
            acc[3][0] += av.w * bv.x; acc[3][1] += av.w * bv.y; acc[3][2] += av.w * bv.z; acc[3][3] += av.w * bv.w;
        }
    }
    if (tid < 64) x2s[tid] = nsum;
    else if (tid < 128) y2s[tid - 64] = nsum;
    __syncthreads();

    // epilogue: D[i][j] = x2[i] + y2[j] - 2*dot into block-anti-diagonal layout
    const int ib = i0 + ty * 4, jb = j0 + tx * 4;
    if (ib >= T_) return;   // ib 4-aligned, T_=800 -> all-or-nothing
    float xs2[4], ys2[4];
    #pragma unroll
    for (int r = 0; r < 4; ++r) xs2[r] = x2s[ty * 4 + r];
    #pragma unroll
    for (int c = 0; c < 4; ++c) ys2[c] = y2s[tx * 4 + c];

    const int tblk = ib >> 2;
    float* __restrict__ D2b = Dm + (size_t)kb * SLAB2_;
    #pragma unroll
    for (int c = 0; c < 4; ++c) {
        int j = jb + c;
        if (j >= T_) continue;
        int d2 = tblk + j;
        int sl = tblk - tmin_of(d2);
        if ((unsigned)sl > (unsigned)(W2_ - 1)) continue;   // out of DP band: never read
        float4 o;
        o.x = xs2[0] + ys2[c] - 2.f * acc[0][c];
        o.y = xs2[1] + ys2[c] - 2.f * acc[1][c];
        o.z = xs2[2] + ys2[c] - 2.f * acc[2][c];
        o.w = xs2[3] + ys2[c] - 2.f * acc[3][c];
        *(float4*)(D2b + (size_t)d2 * (W2_ * 4) + sl * 4) = o;
    }
}

// ---------------------------------------------------------------- banded hard-min DTW, r=4 systolic
// One block (256 thr = 4 waves) per problem; 1 wave per SIMD. Thread t owns DP
// rows 4t+1..4t+4 (1-based), sweeps columns with lane skew 1, wave skew G=80,
// barrier every 8 steps. R8: loads hoisted into per-phase batches (3 rotating
// register buffers, 2-phase lookahead, explicit vmcnt(16)); no per-step
// act-select (out-of-band values carry >=125*256 cost, never win a min —
// see R8 analysis); min3-form cells.
constexpr int G3_   = 80;
constexpr int NPH3_ = 132;   // 132*8 = 1056 > last active step 1046; 132 = 3*44

__device__ __forceinline__ void lds_barrier_keep_vmcnt() {
    asm volatile("" ::: "memory");
    // simm16: vmcnt=63 (keep global loads in flight), expcnt=7, lgkmcnt=0
    __builtin_amdgcn_s_waitcnt(0xC07F);
    __builtin_amdgcn_s_barrier();
    asm volatile("" ::: "memory");
}

__device__ __forceinline__ float wave_shr1(float x) {
    // DPP wave_shr1 (0x138): lane l gets lane l-1's value; lane 0 -> 0 (overridden)
    int v = __builtin_amdgcn_update_dpp(0, __float_as_int(x), 0x138, 0xf, 0xf, true);
    return __int_as_float(v);
}

__global__ __launch_bounds__(256) void dtw_hard_kernel(const float* __restrict__ Dm,
                                                       float* __restrict__ dtwv) {
    __shared__ float ring[3 * 64];
    const int kb  = blockIdx.x;
    const int tid = threadIdx.x;
    const int l = tid & 63;
    const int wu = __builtin_amdgcn_readfirstlane(tid >> 6);
    const bool is_l63w = (l == 63) && (wu < 3);    // ring writers
    const bool is_res  = (tid == 199);             // rows 797..800 -> result lane
    const float* __restrict__ Dd = Dm + (size_t)kb * SLAB2_;

    const float dg1 = (tid == 0) ? 0.f : BIGV;     // R[i-1][0] override at jj==1
    const int goff = G3_ * wu;
    const int wm1 = (wu > 0 ? wu - 1 : 0) * 64;
    const int low_w  = max(1, 256 * wu - 127);
    const int high_w = min(800, 256 * wu + 124);
    const int rslot = wu * 64;

    if (tid < 192) ring[tid] = BIGV;
    __syncthreads();

    // DP state: R[4t+1..4t+4][jj-1] in registers; tprev = R[4t][jj-1]
    float r0s = BIGV, r1s = BIGV, r2s = BIGV, r3s = BIGV;
    float tprev = BIGV;
    float res = 0.f;
    int jj = 1 - goff - l;                         // this lane's column at step 0

    // Batched coalesced clamped D2 loads for steps [s_base, s_base+8)
    auto batch_load = [&](float4 (&buf)[8], int s_base) {
        #pragma unroll
        for (int k = 0; k < 8; ++k) {
            int d2 = s_base + k - 16 * wu;         // wave-uniform
            d2 = d2 < 0 ? 0 : (d2 > PD2_ - 1 ? PD2_ - 1 : d2);
            int sl = 64 * wu - tmin_of(d2) + l;    // per-lane, consecutive
            sl = sl < 0 ? 0 : (sl > W2_ - 1 ? W2_ - 1 : sl);
            buf[k] = *(const float4*)(Dd + (size_t)d2 * (W2_ * 4) + sl * 4);
        }
    };

    float rvA[8], rvB[8], rvC[8];
    auto prefetch_ring = [&](float (&rv)[8], int pp) {   // values consumed during phase pp
        #pragma unroll
        for (int k = 0; k < 8; ++k) {
            int j0 = 8 * pp + k + 1 - goff;              // lane-0 column at step 8*pp+k
            float rr = ring[wm1 + (j0 & 63)];
            rv[k] = (wu > 0 && j0 >= low_w && j0 <= high_w) ? rr : BIGV;
        }
    };

    auto run8 = [&](const float4 (&buf)[8], const float (&rv)[8]) {
        #pragma unroll
        for (int k = 0; k < 8; ++k) {
            float4 d = buf[k];
            float tin  = wave_shr1(r3s);                 // lane l-1's bottom value (prev step)
            float tcur = (l == 0) ? rv[k] : tin;         // R[i0-1][jj]
            float dg   = (jj == 1) ? dg1 : tprev;        // R[i0-1][jj-1]
            float dxW = d.x + WARP_V;
            float n0 = fminf(fminf(dg + d.x, tcur + dxW), r0s + dxW);   // v_min3
            float dyW = d.y + WARP_V;
            float n1 = fminf(fminf(r0s + d.y, n0 + dyW), r1s + dyW);
            float dzW = d.z + WARP_V;
            float n2 = fminf(fminf(r1s + d.z, n1 + dzW), r2s + dzW);
            float dwW = d.w + WARP_V;
            float n3 = fminf(fminf(r2s + d.w, n2 + dwW), r3s + dwW);
            if (is_l63w) ring[rslot + (jj & 63)] = n3;
            if (jj == 800) res = n3;                     // R[800][800] for the result lane
            r0s = n0; r1s = n1; r2s = n2; r3s = n3;
            tprev = tcur;
            ++jj;
        }
    };

    // preload phases 0 and 1; phase 0's ring values are all masked-BIG anyway
    float4 bufA[8], bufB[8], bufC[8];
    batch_load(bufA, 0);
    batch_load(bufB, 8);
    prefetch_ring(rvA, 0);

    int sp = 0;
    for (int p = 0; p < NPH3_; p += 3) {
        batch_load(bufC, sp + 16);
        asm volatile("s_waitcnt vmcnt(16)" ::: "memory");   // bufA complete; B,C in flight
        prefetch_ring(rvB, p + 1);
        run8(bufA, rvA);
        lds_barrier_keep_vmcnt();
        sp += 8;

        batch_load(bufA, sp + 16);
        asm volatile("s_waitcnt vmcnt(16)" ::: "memory");   // bufB complete
        prefetch_ring(rvC, p + 2);
        run8(bufB, rvB);
        lds_barrier_keep_vmcnt();
        sp += 8;

        batch_load(bufB, sp + 16);
        asm volatile("s_waitcnt vmcnt(16)" ::: "memory");   // bufC complete
        prefetch_ring(rvA, p + 3);
        run8(bufC, rvC);
        lds_barrier_keep_vmcnt();
        sp += 8;
    }

    if (is_res) dtwv[kb] = res;
}

// ---------------------------------------------------------------- finalize (scalars)
__global__ void finalize_kernel(const float* __restrict__ dtwv, const int* __restrict__ mel_lens,
                                const int* __restrict__ src_lens, const float* __restrict__ durations,
                                const float* __restrict__ mus, const float* __restrict__ log_vars,
                                const int* __restrict__ step, float* __restrict__ out) {
    const int lane = threadIdx.x;  // 64 threads, one wave

    float v = (lane < KB_) ? dtwv[lane] : 0.f;
    for (int o = 32; o; o >>= 1) v += __shfl_down(v, o);

    float w = (lane < B_) ? 1.f / (K_ * (float)mel_lens[lane]) : 0.f;
    for (int o = 32; o; o >>= 1) w += __shfl_down(w, o);

    float du = 0.f;
    if (lane < B_) {
        float s = 0.f;
        for (int j = 0; j < S_; ++j) s += durations[lane * S_ + j];
        du = fabsf(s - (float)mel_lens[lane]) / (float)src_lens[lane];
    }
    for (int o = 32; o; o >>= 1) du += __shfl_down(du, o);

    float kl = 0.f;
    for (int j = lane; j < B_ * Z_; j += 64) {
        float muv = mus[j], lv = log_vars[j];
        kl += 1.f + lv - muv * muv - expf(lv);
    }
    for (int o = 32; o; o >>= 1) kl += __shfl_down(kl, o);

    if (lane == 0) {
        float mel_iter_loss = v / (float)B_;
        float mel_loss = mel_iter_loss * (w / (float)B_);
        float dur_loss = 2.0f * du / (float)B_;
        float kl_loss = -0.5f * kl;
        int st = step[0];
        float beta = (st < 2000) ? 0.f : ((st >= 8000) ? 1.f : (float)(st - 2000) / 6000.f);
        out[0] = mel_loss + dur_loss + beta * kl_loss;
        out[1] = mel_loss;
        out[2] = dur_loss;
        out[3] = kl_loss;
        out[4] = beta;
    }
}

// ---------------------------------------------------------------- launch
extern "C" void kernel_launch(void* const* d_in, const int* in_sizes, int n_in,
                              void* d_out, int out_size, void* d_ws, size_t ws_size,
                              hipStream_t stream) {
    const float* mel_iters   = (const float*)d_in[0];
    const float* mel_targets = (const float*)d_in[1];
    const int*   mel_lens    = (const int*)d_in[2];
    const int*   src_lens    = (const int*)d_in[3];
    const float* durations   = (const float*)d_in[4];
    const float* mus         = (const float*)d_in[5];
    const float* log_vars    = (const float*)d_in[6];
    const int*   step        = (const int*)d_in[7];
    float* out = (float*)d_out;

    float* ws   = (float*)d_ws;
    float* Dm   = ws;                              // 32 * 208,000 floats (26.6 MB)
    float* dtwv = Dm + (size_t)KB_ * SLAB2_;       //        32

    gemm_band<<<dim3(5, 13, KB_), 256, 0, stream>>>(mel_iters, mel_targets, Dm);

    dtw_hard_kernel<<<KB_, 256, 0, stream>>>(Dm, dtwv);

    finalize_kernel<<<1, 64, 0, stream>>>(dtwv, mel_lens, src_lens, durations, mus, log_vars, step, out);
}